// Round 1
// baseline (774.086 us; speedup 1.0000x reference)
//
#include <hip/hip_runtime.h>
#include <hip/hip_bf16.h>
#include <stdint.h>

typedef __attribute__((ext_vector_type(4))) float  floatx4;
typedef __attribute__((ext_vector_type(8))) short  shortx8;

__device__ __forceinline__ unsigned short f2bf(float f) {
    unsigned int u = __builtin_bit_cast(unsigned int, f);
    u += 0x7FFFu + ((u >> 16) & 1u);
    return (unsigned short)(u >> 16);
}
__device__ __forceinline__ float bf2f(unsigned short h) {
    unsigned int u = (unsigned int)h << 16;
    return __builtin_bit_cast(float, u);
}

__device__ __forceinline__ uint4 pack8(float4 a, float4 b) {
    uint4 r;
    r.x = (unsigned)f2bf(a.x) | ((unsigned)f2bf(a.y) << 16);
    r.y = (unsigned)f2bf(a.z) | ((unsigned)f2bf(a.w) << 16);
    r.z = (unsigned)f2bf(b.x) | ((unsigned)f2bf(b.y) << 16);
    r.w = (unsigned)f2bf(b.z) | ((unsigned)f2bf(b.w) << 16);
    return r;
}

// async global->LDS, 16B per lane. LDS dest must be (wave-uniform base + lane*16).
__device__ __forceinline__ void gload16(const ushort* g, ushort* l) {
    __builtin_amdgcn_global_load_lds(
        (const __attribute__((address_space(1))) unsigned int*)g,
        (__attribute__((address_space(3))) unsigned int*)l, 16, 0, 0);
}

// ---------------- merged cast: memory->bf16 and decoder->concat left half ----------------
__global__ __launch_bounds__(256) void cast_both(const float* __restrict__ mem,
                                                 const float* __restrict__ dec,
                                                 ushort* __restrict__ mem_bf,
                                                 ushort* __restrict__ concat) {
    if (blockIdx.x < 4096) {
        long long i = ((long long)blockIdx.x * 256 + threadIdx.x) * 8;
        const float4* p = (const float4*)(mem + i);
        *(uint4*)(mem_bf + i) = pack8(p[0], p[1]);
    } else {
        long long i = ((long long)(blockIdx.x - 4096) * 256 + threadIdx.x) * 8;
        long long r = i >> 10, c = i & 1023;
        const float4* p = (const float4*)(dec + i);
        *(uint4*)(concat + r * 2048 + c) = pack8(p[0], p[1]);
    }
}

// ---------------- weight transpose-cast: W[K][N] fp32 -> WT[N][K] bf16 ----------------
__global__ __launch_bounds__(256) void wtrans(const float* __restrict__ W,
                                              ushort* __restrict__ WT, int K, int N) {
    __shared__ float t[32][33];
    int tx = threadIdx.x, ty = threadIdx.y;
    int bx = blockIdx.x * 32;  // n
    int by = blockIdx.y * 32;  // k
    #pragma unroll
    for (int i = 0; i < 4; i++)
        t[ty + 8 * i][tx] = W[(size_t)(by + ty + 8 * i) * N + bx + tx];
    __syncthreads();
    #pragma unroll
    for (int i = 0; i < 4; i++)
        WT[(size_t)(bx + ty + 8 * i) * K + by + tx] = f2bf(t[tx][ty + 8 * i]);
}

// batched version for the three 1024x1024 weights (z selects which)
__global__ __launch_bounds__(256) void wtrans3(const float* __restrict__ W0,
                                               const float* __restrict__ W1,
                                               const float* __restrict__ W2,
                                               ushort* __restrict__ T0,
                                               ushort* __restrict__ T1,
                                               ushort* __restrict__ T2) {
    __shared__ float t[32][33];
    const float* W = blockIdx.z == 0 ? W0 : (blockIdx.z == 1 ? W1 : W2);
    ushort* WT     = blockIdx.z == 0 ? T0 : (blockIdx.z == 1 ? T1 : T2);
    int tx = threadIdx.x, ty = threadIdx.y;
    int bx = blockIdx.x * 32;
    int by = blockIdx.y * 32;
    #pragma unroll
    for (int i = 0; i < 4; i++)
        t[ty + 8 * i][tx] = W[(size_t)(by + ty + 8 * i) * 1024 + bx + tx];
    __syncthreads();
    #pragma unroll
    for (int i = 0; i < 4; i++)
        WT[(size_t)(bx + ty + 8 * i) * 1024 + by + tx] = f2bf(t[tx][ty + 8 * i]);
}

// ---------------- V transpose per (b,h): V[(b*1024+k)*1024+h*128+d] -> VT[((h*8+b)*128+d)*1024+k]
__global__ __launch_bounds__(256) void vtrans(const ushort* __restrict__ V,
                                              ushort* __restrict__ VT) {
    __shared__ ushort t[32][33];
    int tx = threadIdx.x, ty = threadIdx.y;
    int bk = blockIdx.x * 32;  // k
    int bd = blockIdx.y * 32;  // d
    int z = blockIdx.z;
    int b = z >> 3, h = z & 7;
    #pragma unroll
    for (int i = 0; i < 4; i++)
        t[ty + 8 * i][tx] = V[((size_t)(b * 1024 + bk + ty + 8 * i)) * 1024 + h * 128 + bd + tx];
    __syncthreads();
    #pragma unroll
    for (int i = 0; i < 4; i++)
        VT[((size_t)((h * 8 + b) * 128 + bd + ty + 8 * i)) * 1024 + bk + tx] = t[tx][ty + 8 * i];
}

// ---------------- GEMM: C[m][n] = sum_k A[m][k] * Bt[n][k] (bf16 in, bf16/fp32 out) ----
// m97 structure: 128x128 tile, BK=64, linear LDS (stride 64), global_load_lds staging,
// 2-barrier K-loop. [m151: gload_lds 874 TF vs reg-staging 646 TF at this structure]
template <typename TC>
__global__ __launch_bounds__(256) void gemm_bt(
    const ushort* __restrict__ A, const ushort* __restrict__ Bt, TC* __restrict__ C,
    int K, int lda, int ldb, int ldc) {
    __shared__ ushort As[128 * 64];
    __shared__ ushort Bs[128 * 64];

    int tid = threadIdx.x;
    int bm = blockIdx.y * 128, bn = blockIdx.x * 128;
    int l = tid & 63, wid = tid >> 6;
    int l16 = l & 15, quad = l >> 4;
    int wm = (wid & 1) * 64, wn = (wid >> 1) * 64;

    // staging coords: thread covers 16B at (srow, scol); LDS byte off = tid*16 per it-step
    int srow = tid >> 3;          // 0..31
    int scol = (tid & 7) * 8;     // 0,8,..,56

    floatx4 acc[4][4];
    #pragma unroll
    for (int i = 0; i < 4; i++)
        #pragma unroll
        for (int j = 0; j < 4; j++)
            acc[i][j] = {0.0f, 0.0f, 0.0f, 0.0f};

    for (int kt = 0; kt < K; kt += 64) {
        #pragma unroll
        for (int it = 0; it < 4; it++) {
            int row = it * 32 + srow;
            gload16(A + (size_t)(bm + row) * lda + kt + scol, &As[row * 64 + scol]);
            gload16(Bt + (size_t)(bn + row) * ldb + kt + scol, &Bs[row * 64 + scol]);
        }
        __syncthreads();
        #pragma unroll
        for (int kk = 0; kk < 64; kk += 32) {
            shortx8 af[4], bfr[4];
            #pragma unroll
            for (int i = 0; i < 4; i++)
                af[i] = *(const shortx8*)&As[(wm + i * 16 + l16) * 64 + kk + quad * 8];
            #pragma unroll
            for (int j = 0; j < 4; j++)
                bfr[j] = *(const shortx8*)&Bs[(wn + j * 16 + l16) * 64 + kk + quad * 8];
            #pragma unroll
            for (int i = 0; i < 4; i++)
                #pragma unroll
                for (int j = 0; j < 4; j++)
                    acc[i][j] = __builtin_amdgcn_mfma_f32_16x16x32_bf16(af[i], bfr[j], acc[i][j], 0, 0, 0);
        }
        __syncthreads();
    }

    #pragma unroll
    for (int i = 0; i < 4; i++) {
        #pragma unroll
        for (int j = 0; j < 4; j++) {
            int row0 = bm + wm + i * 16 + quad * 4;
            int col = bn + wn + j * 16 + l16;
            #pragma unroll
            for (int r = 0; r < 4; r++) {
                float v = acc[i][j][r];
                size_t idx = (size_t)(row0 + r) * ldc + col;
                if constexpr (__is_same(TC, float)) C[idx] = v;
                else C[idx] = f2bf(v);
            }
        }
    }
}

// ---------------- fused attention: QK^T -> mask -> softmax -> *qmask -> attns + PV ------
// One block = 16 Q-rows of one (h,b). K and VT are L2-resident (256 KB per (b,h),
// reused by 64 blocks) -> load MFMA B-fragments DIRECTLY from global, no LDS staging
// [m169: dropping L2-fit staging was +26%]. Full exp'd score row kept in LDS (bf16).
__global__ __launch_bounds__(256) void fused_attn(
    const ushort* __restrict__ Qp, const ushort* __restrict__ Kp,
    const ushort* __restrict__ VT, const int* __restrict__ mask,
    const float* __restrict__ qmask, float* __restrict__ attns,
    ushort* __restrict__ concat) {
    __shared__ ushort Qs[16 * 136];        // Q tile
    __shared__ ushort Ss[16 * 1032];       // exp'd scores bf16, stride 1032 (pad 8)
    __shared__ float rowpart[16][17];
    __shared__ float scale_s[16];

    const int b = blockIdx.z, h = blockIdx.y, q0 = blockIdx.x * 16;
    const int tid = threadIdx.x;
    const int w = tid >> 6, l = tid & 63;
    const int l16 = l & 15, quad = l >> 4;
    const float sc = 0.08838834764831845f;  // 1/sqrt(128)

    // ---- load Q tile (16 x 128) ----
    {
        int row = tid >> 4, col = (tid & 15) * 8;
        *(uint4*)&Qs[row * 136 + col] =
            *(const uint4*)(Qp + (size_t)(b * 1024 + q0 + row) * 1024 + h * 128 + col);
    }
    __syncthreads();

    // preload A-fragments (reused for all k-tiles)
    shortx8 af[4];
    #pragma unroll
    for (int kk = 0; kk < 4; kk++)
        af[kk] = *(const shortx8*)&Qs[l16 * 136 + kk * 32 + quad * 8];

    // ---- QK^T + mask + exp; B-fragments direct from global (16B/lane, 16 lines/wave) ----
    const size_t mbase = (size_t)b * 1048576 + (size_t)q0 * 1024;
    for (int c = 0; c < 16; ++c) {
        int k0 = c * 64 + w * 16;  // this wave's 16 K-rows
        const ushort* Kr = Kp + (size_t)(b * 1024 + k0 + l16) * 1024 + h * 128 + quad * 8;
        floatx4 acc = {0.0f, 0.0f, 0.0f, 0.0f};
        #pragma unroll
        for (int kk = 0; kk < 4; ++kk)
            acc = __builtin_amdgcn_mfma_f32_16x16x32_bf16(af[kk], *(const shortx8*)(Kr + kk * 32), acc, 0, 0, 0);
        #pragma unroll
        for (int r = 0; r < 4; ++r) {
            int q = quad * 4 + r;
            int m = mask[mbase + (size_t)q * 1024 + k0 + l16];
            float v = m ? 0.0f : __expf(acc[r] * sc);
            Ss[q * 1032 + k0 + l16] = f2bf(v);
        }
    }
    __syncthreads();

    // ---- row sums ----
    {
        int row = tid >> 4, cs = (tid & 15) * 64;
        float s = 0.0f;
        #pragma unroll
        for (int i = 0; i < 8; ++i) {
            shortx8 v = *(const shortx8*)&Ss[row * 1032 + cs + i * 8];
            #pragma unroll
            for (int j = 0; j < 8; ++j) s += bf2f((unsigned short)v[j]);
        }
        rowpart[row][tid & 15] = s;
    }
    __syncthreads();
    if (tid < 16) {
        float s = 0.0f;
        #pragma unroll
        for (int i = 0; i < 16; ++i) s += rowpart[tid][i];
        scale_s[tid] = qmask[b * 1024 + q0 + tid] / s;
    }
    __syncthreads();

    // ---- write normalized attns (fp32, includes qmask); nontemporal: 256MB stream-out
    //      never re-read, keep it from evicting L2/L3-resident K/V/mask ----
    {
        int row = tid >> 4;
        float scl = scale_s[row];
        float* arow = attns + ((size_t)((h * 8 + b) * 1024 + q0 + row)) * 1024;
        int c0 = (tid & 15) * 4;
        #pragma unroll
        for (int j = 0; j < 16; ++j) {
            int c = c0 + j * 64;
            ushort4 v = *(const ushort4*)&Ss[row * 1032 + c];
            floatx4 o;
            o.x = bf2f(v.x) * scl;
            o.y = bf2f(v.y) * scl;
            o.z = bf2f(v.z) * scl;
            o.w = bf2f(v.w) * scl;
            __builtin_nontemporal_store(o, (floatx4*)(arow + c));
        }
    }

    // ---- PV: O = P @ V, V-fragments direct from global VT (contiguous 16B/lane) ----
    const size_t vrow0 = (size_t)((h * 8 + b) * 128 + w * 32);
    floatx4 oacc[2] = {{0.0f, 0.0f, 0.0f, 0.0f}, {0.0f, 0.0f, 0.0f, 0.0f}};
    for (int c = 0; c < 16; ++c) {
        #pragma unroll
        for (int ks = 0; ks < 2; ++ks) {
            shortx8 a = *(const shortx8*)&Ss[l16 * 1032 + c * 64 + ks * 32 + quad * 8];
            #pragma unroll
            for (int j = 0; j < 2; ++j) {
                const ushort* vp = VT + (vrow0 + j * 16 + l16) * 1024 + c * 64 + ks * 32 + quad * 8;
                oacc[j] = __builtin_amdgcn_mfma_f32_16x16x32_bf16(a, *(const shortx8*)vp, oacc[j], 0, 0, 0);
            }
        }
    }
    #pragma unroll
    for (int j = 0; j < 2; ++j) {
        #pragma unroll
        for (int r = 0; r < 4; ++r) {
            int q = quad * 4 + r;
            int d = w * 32 + j * 16 + l16;
            float v = oacc[j][r] * scale_s[q];
            concat[(size_t)(b * 1024 + q0 + q) * 2048 + 1024 + h * 128 + d] = f2bf(v);
        }
    }
}

// ---------------- LayerNorm epilogue: x = LN(ffn + bf + decoder) ----------------
__global__ __launch_bounds__(256) void ln_out(const float* __restrict__ ffn,
                                              const float* __restrict__ dec,
                                              const float* __restrict__ bfv,
                                              const float* __restrict__ gamma,
                                              const float* __restrict__ beta,
                                              float* __restrict__ out) {
    __shared__ float sb[8];
    int row = blockIdx.x, tid = threadIdx.x;
    int c = tid * 4;
    size_t base = (size_t)row * 1024 + c;
    float4 x = *(const float4*)(ffn + base);
    float4 d = *(const float4*)(dec + base);
    float4 bb = *(const float4*)(bfv + c);
    x.x += d.x + bb.x; x.y += d.y + bb.y; x.z += d.z + bb.z; x.w += d.w + bb.w;

    float s = x.x + x.y + x.z + x.w;
    float s2 = x.x * x.x + x.y * x.y + x.z * x.z + x.w * x.w;
    #pragma unroll
    for (int o = 32; o; o >>= 1) {
        s += __shfl_down(s, o, 64);
        s2 += __shfl_down(s2, o, 64);
    }
    if ((tid & 63) == 0) { sb[tid >> 6] = s; sb[4 + (tid >> 6)] = s2; }
    __syncthreads();
    s = sb[0] + sb[1] + sb[2] + sb[3];
    s2 = sb[4] + sb[5] + sb[6] + sb[7];
    float mu = s * (1.0f / 1024.0f);
    float var = s2 * (1.0f / 1024.0f) - mu * mu;
    float rs = rsqrtf(var + 1e-5f);

    float4 g = *(const float4*)(gamma + c);
    float4 be = *(const float4*)(beta + c);
    float4 o4;
    o4.x = (x.x - mu) * rs * g.x + be.x;
    o4.y = (x.y - mu) * rs * g.y + be.y;
    o4.z = (x.z - mu) * rs * g.z + be.z;
    o4.w = (x.w - mu) * rs * g.w + be.w;
    *(float4*)(out + base) = o4;
}

extern "C" void kernel_launch(void* const* d_in, const int* in_sizes, int n_in,
                              void* d_out, int out_size, void* d_ws, size_t ws_size,
                              hipStream_t stream) {
    const float* memory  = (const float*)d_in[0];   // (8,1024,1024)
    const float* decoder = (const float*)d_in[1];   // (8,1024,1024)
    const float* qmask   = (const float*)d_in[2];   // (8,1024)
    const float* Wk      = (const float*)d_in[3];   // (1024,1024)
    const float* Wv      = (const float*)d_in[4];
    const float* Wq      = (const float*)d_in[5];
    const float* Wf      = (const float*)d_in[6];   // (2048,1024)
    const float* bfv     = (const float*)d_in[7];   // (1024,)
    const float* gamma   = (const float*)d_in[8];
    const float* beta    = (const float*)d_in[9];
    const int*   mask    = (const int*)d_in[10];    // (8,1024,1024) 0/1

    float* xout  = (float*)d_out;                   // (8,1024,1024)
    float* attns = xout + 8388608LL;                // (64,1024,1024)

    char* w = (char*)d_ws;
    ushort* mem_bf = (ushort*)(w + 0);              // 16 MB (dead after projections)
    ushort* Kp     = (ushort*)(w + (16LL << 20));   // 16 MB (dead after fused_attn)
    float*  ffn    = (float*)(w + 0);               // 32 MB, written after Kp dead
    ushort* Qp     = (ushort*)(w + (32LL << 20));   // 16 MB
    ushort* Vp     = (ushort*)(w + (48LL << 20));   // 16 MB
    ushort* VT     = (ushort*)(w + (64LL << 20));   // 16 MB
    ushort* concat = (ushort*)(w + (80LL << 20));   // 32 MB (8192 x 2048 bf16)
    ushort* WkT    = (ushort*)(w + (112LL << 20));  // 2 MB
    ushort* WvT    = (ushort*)(w + (114LL << 20));  // 2 MB
    ushort* WqT    = (ushort*)(w + (116LL << 20));  // 2 MB
    ushort* WfT    = (ushort*)(w + (118LL << 20));  // 4 MB

    // 1) casts (merged)
    cast_both<<<8192, 256, 0, stream>>>(memory, decoder, mem_bf, concat);
    // 2) weight transposes (batched 3x 1024^2, plus Wf)
    wtrans3<<<dim3(32, 32, 3), dim3(32, 8), 0, stream>>>(Wk, Wv, Wq, WkT, WvT, WqT);
    wtrans<<<dim3(32, 64), dim3(32, 8), 0, stream>>>(Wf, WfT, 2048, 1024);
    // 3) projections
    gemm_bt<ushort><<<dim3(8, 64), 256, 0, stream>>>(mem_bf, WkT, Kp, 1024, 1024, 1024, 1024);
    gemm_bt<ushort><<<dim3(8, 64), 256, 0, stream>>>(mem_bf, WvT, Vp, 1024, 1024, 1024, 1024);
    gemm_bt<ushort><<<dim3(8, 64), 256, 0, stream>>>(concat, WqT, Qp, 1024, 2048, 1024, 1024);
    // 4) V transpose per (b,h)
    vtrans<<<dim3(32, 4, 64), dim3(32, 8), 0, stream>>>(Vp, VT);
    // 5) fused QK^T+softmax+qmask -> attns, and PV -> concat right half
    fused_attn<<<dim3(64, 8, 8), 256, 0, stream>>>(Qp, Kp, VT, mask, qmask, attns, concat);
    // 6) FFN: concat(8192x2048) @ WfT^T -> ffn fp32
    gemm_bt<float><<<dim3(8, 64), 256, 0, stream>>>(concat, WfT, ffn, 2048, 2048, 2048, 1024);
    // 7) bias + residual + LayerNorm -> x output
    ln_out<<<8192, 256, 0, stream>>>(ffn, decoder, bfv, gamma, beta, xout);
}

// Round 2
// 752.399 us; speedup vs baseline: 1.0288x; 1.0288x over previous
//
#include <hip/hip_runtime.h>
#include <hip/hip_bf16.h>
#include <stdint.h>

typedef __attribute__((ext_vector_type(4))) float  floatx4;
typedef __attribute__((ext_vector_type(8))) short  shortx8;

__device__ __forceinline__ unsigned short f2bf(float f) {
    unsigned int u = __builtin_bit_cast(unsigned int, f);
    u += 0x7FFFu + ((u >> 16) & 1u);
    return (unsigned short)(u >> 16);
}
__device__ __forceinline__ float bf2f(unsigned short h) {
    unsigned int u = (unsigned int)h << 16;
    return __builtin_bit_cast(float, u);
}

__device__ __forceinline__ uint4 pack8(float4 a, float4 b) {
    uint4 r;
    r.x = (unsigned)f2bf(a.x) | ((unsigned)f2bf(a.y) << 16);
    r.y = (unsigned)f2bf(a.z) | ((unsigned)f2bf(a.w) << 16);
    r.z = (unsigned)f2bf(b.x) | ((unsigned)f2bf(b.y) << 16);
    r.w = (unsigned)f2bf(b.z) | ((unsigned)f2bf(b.w) << 16);
    return r;
}

// async global->LDS, 16B per lane. LDS dest must be (wave-uniform base + lane*16).
__device__ __forceinline__ void gload16(const ushort* g, ushort* l) {
    __builtin_amdgcn_global_load_lds(
        (const __attribute__((address_space(1))) unsigned int*)g,
        (__attribute__((address_space(3))) unsigned int*)l, 16, 0, 0);
}

// ---------------- merged cast: memory->bf16 and decoder->concat left half ----------------
__global__ __launch_bounds__(256) void cast_both(const float* __restrict__ mem,
                                                 const float* __restrict__ dec,
                                                 ushort* __restrict__ mem_bf,
                                                 ushort* __restrict__ concat) {
    if (blockIdx.x < 4096) {
        long long i = ((long long)blockIdx.x * 256 + threadIdx.x) * 8;
        const float4* p = (const float4*)(mem + i);
        *(uint4*)(mem_bf + i) = pack8(p[0], p[1]);
    } else {
        long long i = ((long long)(blockIdx.x - 4096) * 256 + threadIdx.x) * 8;
        long long r = i >> 10, c = i & 1023;
        const float4* p = (const float4*)(dec + i);
        *(uint4*)(concat + r * 2048 + c) = pack8(p[0], p[1]);
    }
}

// ---------------- mask bitpack: int32 (8,1024,1024) -> 1 bit/elem (1 MB) ----------------
// bit l of word64 w = mask[w*64 + l]  (1 = masked -> exp value 0)
__global__ __launch_bounds__(256) void pack_mask(const int* __restrict__ mask,
                                                 unsigned long long* __restrict__ mb) {
    int gw = (blockIdx.x * 256 + threadIdx.x) >> 6;   // 0..8191
    int l = threadIdx.x & 63;
    #pragma unroll
    for (int i = 0; i < 16; ++i) {
        size_t widx = (size_t)gw * 16 + i;
        unsigned long long m = __ballot(mask[widx * 64 + l] != 0);
        if (l == 0) mb[widx] = m;
    }
}

// ---------------- weight transpose-cast: W[K][N] fp32 -> WT[N][K] bf16 ----------------
__global__ __launch_bounds__(256) void wtrans(const float* __restrict__ W,
                                              ushort* __restrict__ WT, int K, int N) {
    __shared__ float t[32][33];
    int tx = threadIdx.x, ty = threadIdx.y;
    int bx = blockIdx.x * 32;  // n
    int by = blockIdx.y * 32;  // k
    #pragma unroll
    for (int i = 0; i < 4; i++)
        t[ty + 8 * i][tx] = W[(size_t)(by + ty + 8 * i) * N + bx + tx];
    __syncthreads();
    #pragma unroll
    for (int i = 0; i < 4; i++)
        WT[(size_t)(bx + ty + 8 * i) * K + by + tx] = f2bf(t[tx][ty + 8 * i]);
}

// batched version for the three 1024x1024 weights (z selects which)
__global__ __launch_bounds__(256) void wtrans3(const float* __restrict__ W0,
                                               const float* __restrict__ W1,
                                               const float* __restrict__ W2,
                                               ushort* __restrict__ T0,
                                               ushort* __restrict__ T1,
                                               ushort* __restrict__ T2) {
    __shared__ float t[32][33];
    const float* W = blockIdx.z == 0 ? W0 : (blockIdx.z == 1 ? W1 : W2);
    ushort* WT     = blockIdx.z == 0 ? T0 : (blockIdx.z == 1 ? T1 : T2);
    int tx = threadIdx.x, ty = threadIdx.y;
    int bx = blockIdx.x * 32;
    int by = blockIdx.y * 32;
    #pragma unroll
    for (int i = 0; i < 4; i++)
        t[ty + 8 * i][tx] = W[(size_t)(by + ty + 8 * i) * 1024 + bx + tx];
    __syncthreads();
    #pragma unroll
    for (int i = 0; i < 4; i++)
        WT[(size_t)(bx + ty + 8 * i) * 1024 + by + tx] = f2bf(t[tx][ty + 8 * i]);
}

// ---------------- V transpose per (b,h): V[(b*1024+k)*1024+h*128+d] -> VT[((h*8+b)*128+d)*1024+k]
__global__ __launch_bounds__(256) void vtrans(const ushort* __restrict__ V,
                                              ushort* __restrict__ VT) {
    __shared__ ushort t[32][33];
    int tx = threadIdx.x, ty = threadIdx.y;
    int bk = blockIdx.x * 32;  // k
    int bd = blockIdx.y * 32;  // d
    int z = blockIdx.z;
    int b = z >> 3, h = z & 7;
    #pragma unroll
    for (int i = 0; i < 4; i++)
        t[ty + 8 * i][tx] = V[((size_t)(b * 1024 + bk + ty + 8 * i)) * 1024 + h * 128 + bd + tx];
    __syncthreads();
    #pragma unroll
    for (int i = 0; i < 4; i++)
        VT[((size_t)((h * 8 + b) * 128 + bd + ty + 8 * i)) * 1024 + bk + tx] = t[tx][ty + 8 * i];
}

// ---------------- shared GEMM core: C[m][n] = sum_k A[m][k]*Bt[n][k] --------------------
// m97 structure: 128x128 tile, BK=64, linear LDS, global_load_lds staging, 2-barrier loop.
template <typename TC>
__device__ __forceinline__ void gemm_core(ushort* As, ushort* Bs,
                                          const ushort* __restrict__ A,
                                          const ushort* __restrict__ Bt, TC* __restrict__ C,
                                          int kbeg, int kend, int lda, int ldb, int ldc,
                                          int bm, int bn) {
    int tid = threadIdx.x;
    int l = tid & 63, wid = tid >> 6;
    int l16 = l & 15, quad = l >> 4;
    int wm = (wid & 1) * 64, wn = (wid >> 1) * 64;
    int srow = tid >> 3;          // 0..31
    int scol = (tid & 7) * 8;     // 0..56

    floatx4 acc[4][4];
    #pragma unroll
    for (int i = 0; i < 4; i++)
        #pragma unroll
        for (int j = 0; j < 4; j++)
            acc[i][j] = {0.0f, 0.0f, 0.0f, 0.0f};

    for (int kt = kbeg; kt < kend; kt += 64) {
        #pragma unroll
        for (int it = 0; it < 4; it++) {
            int row = it * 32 + srow;
            gload16(A + (size_t)(bm + row) * lda + kt + scol, &As[row * 64 + scol]);
            gload16(Bt + (size_t)(bn + row) * ldb + kt + scol, &Bs[row * 64 + scol]);
        }
        __syncthreads();
        #pragma unroll
        for (int kk = 0; kk < 64; kk += 32) {
            shortx8 af[4], bfr[4];
            #pragma unroll
            for (int i = 0; i < 4; i++)
                af[i] = *(const shortx8*)&As[(wm + i * 16 + l16) * 64 + kk + quad * 8];
            #pragma unroll
            for (int j = 0; j < 4; j++)
                bfr[j] = *(const shortx8*)&Bs[(wn + j * 16 + l16) * 64 + kk + quad * 8];
            #pragma unroll
            for (int i = 0; i < 4; i++)
                #pragma unroll
                for (int j = 0; j < 4; j++)
                    acc[i][j] = __builtin_amdgcn_mfma_f32_16x16x32_bf16(af[i], bfr[j], acc[i][j], 0, 0, 0);
        }
        __syncthreads();
    }

    #pragma unroll
    for (int i = 0; i < 4; i++) {
        #pragma unroll
        for (int j = 0; j < 4; j++) {
            int row0 = bm + wm + i * 16 + quad * 4;
            int col = bn + wn + j * 16 + l16;
            #pragma unroll
            for (int r = 0; r < 4; r++) {
                float v = acc[i][j][r];
                size_t idx = (size_t)(row0 + r) * ldc + col;
                if constexpr (__is_same(TC, float)) C[idx] = v;
                else C[idx] = f2bf(v);
            }
        }
    }
}

// all three projections in one launch (z selects) -> 1536 blocks, ~3 blocks/CU resident
__global__ __launch_bounds__(256) void gemm_proj3(
    const ushort* __restrict__ mem_bf, const ushort* __restrict__ concat,
    const ushort* __restrict__ WkT, const ushort* __restrict__ WvT,
    const ushort* __restrict__ WqT,
    ushort* __restrict__ Kp, ushort* __restrict__ Vp, ushort* __restrict__ Qp) {
    __shared__ ushort As[128 * 64];
    __shared__ ushort Bs[128 * 64];
    const ushort* A; const ushort* Bt; ushort* C; int lda;
    if (blockIdx.z == 0)      { A = mem_bf; Bt = WkT; C = Kp; lda = 1024; }
    else if (blockIdx.z == 1) { A = mem_bf; Bt = WvT; C = Vp; lda = 1024; }
    else                      { A = concat; Bt = WqT; C = Qp; lda = 2048; }
    gemm_core<ushort>(As, Bs, A, Bt, C, 0, 1024, lda, 1024, 1024,
                      blockIdx.y * 128, blockIdx.x * 128);
}

// FFN split-K (z halves of K=2048) into two partial fp32 buffers, summed in ln_out
__global__ __launch_bounds__(256) void gemm_ffn(
    const ushort* __restrict__ concat, const ushort* __restrict__ WfT,
    float* __restrict__ ffn0, float* __restrict__ ffn1) {
    __shared__ ushort As[128 * 64];
    __shared__ ushort Bs[128 * 64];
    int z = blockIdx.z;
    gemm_core<float>(As, Bs, concat, WfT, z ? ffn1 : ffn0,
                     z * 1024, z * 1024 + 1024, 2048, 2048, 1024,
                     blockIdx.y * 128, blockIdx.x * 128);
}

// ---------------- fused attention: QK^T -> mask -> softmax -> *qmask -> attns + PV ------
// One block = 16 Q-rows of one (h,b). K/VT are L2-resident -> B-fragments direct from
// global with register depth-1 prefetch (T14). Mask is bitpacked: 2 KB tile in LDS.
// Row-sum fused into QK loop (per-lane fp32 acc + shfl_xor butterfly) -> one less pass.
__global__ __launch_bounds__(256, 4) void fused_attn(
    const ushort* __restrict__ Qp, const ushort* __restrict__ Kp,
    const ushort* __restrict__ VT, const unsigned long long* __restrict__ mb,
    const float* __restrict__ qmask, float* __restrict__ attns,
    ushort* __restrict__ concat) {
    __shared__ ushort Qs[16 * 136];        // Q tile
    __shared__ ushort Ss[16 * 1032];       // exp'd scores bf16, stride 1032 (pad 8)
    __shared__ unsigned Ms[16][34];        // bitpacked mask tile (16 rows x 32 words)
    __shared__ float rowpart[16][5];
    __shared__ float scale_s[16];

    const int b = blockIdx.z, h = blockIdx.y, q0 = blockIdx.x * 16;
    const int tid = threadIdx.x;
    const int w = tid >> 6, l = tid & 63;
    const int l16 = l & 15, quad = l >> 4;
    const float sc = 0.08838834764831845f;  // 1/sqrt(128)

    // ---- load Q tile (16 x 128) + mask tile (16 x 2 uint64) ----
    {
        int row = tid >> 4, col = (tid & 15) * 8;
        *(uint4*)&Qs[row * 136 + col] =
            *(const uint4*)(Qp + (size_t)(b * 1024 + q0 + row) * 1024 + h * 128 + col);
        int pr = tid & 15;
        uint2 mv = ((const uint2*)mb)[(size_t)(b * 1024 + q0 + row) * 16 + pr];
        Ms[row][pr * 2] = mv.x;
        Ms[row][pr * 2 + 1] = mv.y;
    }
    __syncthreads();

    // preload A-fragments (reused for all k-tiles)
    shortx8 af[4];
    #pragma unroll
    for (int kk = 0; kk < 4; kk++)
        af[kk] = *(const shortx8*)&Qs[l16 * 136 + kk * 32 + quad * 8];

    // ---- QK^T + mask + exp, register-pipelined K loads, fused row-sums ----
    const ushort* Kb = Kp + (size_t)(b * 1024 + w * 16 + l16) * 1024 + h * 128 + quad * 8;
    shortx8 kf0 = *(const shortx8*)(Kb + 0);
    shortx8 kf1 = *(const shortx8*)(Kb + 32);
    shortx8 kf2 = *(const shortx8*)(Kb + 64);
    shortx8 kf3 = *(const shortx8*)(Kb + 96);
    float ssum[4] = {0.0f, 0.0f, 0.0f, 0.0f};
    const int bp64 = w * 16 + l16;
    const int wsel = bp64 >> 5, bitp = bp64 & 31;
    for (int c = 0; c < 16; ++c) {
        int cn = c < 15 ? c + 1 : c;
        const ushort* Kn = Kb + (size_t)cn * 65536;  // next iter's 64 K-rows
        shortx8 kn0 = *(const shortx8*)(Kn + 0);
        shortx8 kn1 = *(const shortx8*)(Kn + 32);
        shortx8 kn2 = *(const shortx8*)(Kn + 64);
        shortx8 kn3 = *(const shortx8*)(Kn + 96);
        floatx4 acc = {0.0f, 0.0f, 0.0f, 0.0f};
        __builtin_amdgcn_s_setprio(1);
        acc = __builtin_amdgcn_mfma_f32_16x16x32_bf16(af[0], kf0, acc, 0, 0, 0);
        acc = __builtin_amdgcn_mfma_f32_16x16x32_bf16(af[1], kf1, acc, 0, 0, 0);
        acc = __builtin_amdgcn_mfma_f32_16x16x32_bf16(af[2], kf2, acc, 0, 0, 0);
        acc = __builtin_amdgcn_mfma_f32_16x16x32_bf16(af[3], kf3, acc, 0, 0, 0);
        __builtin_amdgcn_s_setprio(0);
        int k0 = c * 64 + w * 16;
        #pragma unroll
        for (int r = 0; r < 4; ++r) {
            int q = quad * 4 + r;
            unsigned wv = Ms[q][c * 2 + wsel];
            float v = ((wv >> bitp) & 1u) ? 0.0f : __expf(acc[r] * sc);
            ssum[r] += v;
            Ss[q * 1032 + k0 + l16] = f2bf(v);
        }
        kf0 = kn0; kf1 = kn1; kf2 = kn2; kf3 = kn3;
    }

    // ---- reduce row-sums: butterfly over the 16-lane group, combine 4 waves via LDS ----
    #pragma unroll
    for (int r = 0; r < 4; ++r) {
        float s = ssum[r];
        #pragma unroll
        for (int off = 1; off < 16; off <<= 1) s += __shfl_xor(s, off, 16);
        ssum[r] = s;
    }
    if (l16 == 0) {
        #pragma unroll
        for (int r = 0; r < 4; ++r) rowpart[quad * 4 + r][w] = ssum[r];
    }
    __syncthreads();
    if (tid < 16) {
        float s = rowpart[tid][0] + rowpart[tid][1] + rowpart[tid][2] + rowpart[tid][3];
        scale_s[tid] = qmask[b * 1024 + q0 + tid] / s;
    }
    __syncthreads();

    // ---- write normalized attns (fp32, includes qmask); nontemporal stream-out ----
    {
        int row = tid >> 4;
        float scl = scale_s[row];
        float* arow = attns + ((size_t)((h * 8 + b) * 1024 + q0 + row)) * 1024;
        int c0 = (tid & 15) * 4;
        #pragma unroll
        for (int j = 0; j < 16; ++j) {
            int c = c0 + j * 64;
            ushort4 v = *(const ushort4*)&Ss[row * 1032 + c];
            floatx4 o;
            o.x = bf2f(v.x) * scl;
            o.y = bf2f(v.y) * scl;
            o.z = bf2f(v.z) * scl;
            o.w = bf2f(v.w) * scl;
            __builtin_nontemporal_store(o, (floatx4*)(arow + c));
        }
    }

    // ---- PV: O = P @ V, V-fragments direct from global VT, register-pipelined ----
    const size_t vrow0 = (size_t)((h * 8 + b) * 128 + w * 32);
    const ushort* Vb0 = VT + (vrow0 + l16) * 1024 + quad * 8;
    const ushort* Vb1 = VT + (vrow0 + 16 + l16) * 1024 + quad * 8;
    shortx8 v00 = *(const shortx8*)(Vb0);
    shortx8 v01 = *(const shortx8*)(Vb1);
    shortx8 v10 = *(const shortx8*)(Vb0 + 32);
    shortx8 v11 = *(const shortx8*)(Vb1 + 32);
    floatx4 o0 = {0.0f, 0.0f, 0.0f, 0.0f}, o1 = {0.0f, 0.0f, 0.0f, 0.0f};
    for (int c = 0; c < 16; ++c) {
        int cn = c < 15 ? c + 1 : c;
        shortx8 n00 = *(const shortx8*)(Vb0 + cn * 64);
        shortx8 n01 = *(const shortx8*)(Vb1 + cn * 64);
        shortx8 n10 = *(const shortx8*)(Vb0 + cn * 64 + 32);
        shortx8 n11 = *(const shortx8*)(Vb1 + cn * 64 + 32);
        shortx8 pa0 = *(const shortx8*)&Ss[l16 * 1032 + c * 64 + quad * 8];
        shortx8 pa1 = *(const shortx8*)&Ss[l16 * 1032 + c * 64 + 32 + quad * 8];
        __builtin_amdgcn_s_setprio(1);
        o0 = __builtin_amdgcn_mfma_f32_16x16x32_bf16(pa0, v00, o0, 0, 0, 0);
        o1 = __builtin_amdgcn_mfma_f32_16x16x32_bf16(pa0, v01, o1, 0, 0, 0);
        o0 = __builtin_amdgcn_mfma_f32_16x16x32_bf16(pa1, v10, o0, 0, 0, 0);
        o1 = __builtin_amdgcn_mfma_f32_16x16x32_bf16(pa1, v11, o1, 0, 0, 0);
        __builtin_amdgcn_s_setprio(0);
        v00 = n00; v01 = n01; v10 = n10; v11 = n11;
    }
    #pragma unroll
    for (int r = 0; r < 4; ++r) {
        int q = quad * 4 + r;
        float scl = scale_s[q];
        int d = w * 32 + l16;
        size_t base = (size_t)(b * 1024 + q0 + q) * 2048 + 1024 + h * 128;
        concat[base + d]      = f2bf(o0[r] * scl);
        concat[base + d + 16] = f2bf(o1[r] * scl);
    }
}

// ---------------- LayerNorm epilogue: x = LN(ffn0 + ffn1 + bf + decoder) ----------------
__global__ __launch_bounds__(256) void ln_out(const float* __restrict__ ffn0,
                                              const float* __restrict__ ffn1,
                                              const float* __restrict__ dec,
                                              const float* __restrict__ bfv,
                                              const float* __restrict__ gamma,
                                              const float* __restrict__ beta,
                                              float* __restrict__ out) {
    __shared__ float sb[8];
    int row = blockIdx.x, tid = threadIdx.x;
    int c = tid * 4;
    size_t base = (size_t)row * 1024 + c;
    float4 x = *(const float4*)(ffn0 + base);
    float4 y = *(const float4*)(ffn1 + base);
    float4 d = *(const float4*)(dec + base);
    float4 bb = *(const float4*)(bfv + c);
    x.x += y.x + d.x + bb.x; x.y += y.y + d.y + bb.y;
    x.z += y.z + d.z + bb.z; x.w += y.w + d.w + bb.w;

    float s = x.x + x.y + x.z + x.w;
    float s2 = x.x * x.x + x.y * x.y + x.z * x.z + x.w * x.w;
    #pragma unroll
    for (int o = 32; o; o >>= 1) {
        s += __shfl_down(s, o, 64);
        s2 += __shfl_down(s2, o, 64);
    }
    if ((tid & 63) == 0) { sb[tid >> 6] = s; sb[4 + (tid >> 6)] = s2; }
    __syncthreads();
    s = sb[0] + sb[1] + sb[2] + sb[3];
    s2 = sb[4] + sb[5] + sb[6] + sb[7];
    float mu = s * (1.0f / 1024.0f);
    float var = s2 * (1.0f / 1024.0f) - mu * mu;
    float rs = rsqrtf(var + 1e-5f);

    float4 g = *(const float4*)(gamma + c);
    float4 be = *(const float4*)(beta + c);
    float4 o4;
    o4.x = (x.x - mu) * rs * g.x + be.x;
    o4.y = (x.y - mu) * rs * g.y + be.y;
    o4.z = (x.z - mu) * rs * g.z + be.z;
    o4.w = (x.w - mu) * rs * g.w + be.w;
    *(float4*)(out + base) = o4;
}

extern "C" void kernel_launch(void* const* d_in, const int* in_sizes, int n_in,
                              void* d_out, int out_size, void* d_ws, size_t ws_size,
                              hipStream_t stream) {
    const float* memory  = (const float*)d_in[0];   // (8,1024,1024)
    const float* decoder = (const float*)d_in[1];   // (8,1024,1024)
    const float* qmask   = (const float*)d_in[2];   // (8,1024)
    const float* Wk      = (const float*)d_in[3];   // (1024,1024)
    const float* Wv      = (const float*)d_in[4];
    const float* Wq      = (const float*)d_in[5];
    const float* Wf      = (const float*)d_in[6];   // (2048,1024)
    const float* bfv     = (const float*)d_in[7];   // (1024,)
    const float* gamma   = (const float*)d_in[8];
    const float* beta    = (const float*)d_in[9];
    const int*   mask    = (const int*)d_in[10];    // (8,1024,1024) 0/1

    float* xout  = (float*)d_out;                   // (8,1024,1024)
    float* attns = xout + 8388608LL;                // (64,1024,1024)

    char* w = (char*)d_ws;
    ushort* mem_bf = (ushort*)(w + 0);              // 16 MB [cast -> proj]
    ushort* Kp     = (ushort*)(w + (16LL << 20));   // 16 MB [proj -> fused]
    ushort* Qp     = (ushort*)(w + (32LL << 20));   // 16 MB [proj -> fused]
    ushort* Vp     = (ushort*)(w + (48LL << 20));   // 16 MB [proj -> vtrans]
    ushort* VT     = (ushort*)(w + (64LL << 20));   // 16 MB [vtrans -> fused]
    ushort* concat = (ushort*)(w + (80LL << 20));   // 32 MB [cast -> ffn]
    ushort* WkT    = (ushort*)(w + (112LL << 20));  // 2 MB
    ushort* WvT    = (ushort*)(w + (114LL << 20));  // 2 MB
    ushort* WqT    = (ushort*)(w + (116LL << 20));  // 2 MB
    ushort* WfT    = (ushort*)(w + (118LL << 20));  // 4 MB
    // overlays (lifetime-disjoint):
    unsigned long long* mbits = (unsigned long long*)(w + (48LL << 20));  // 1 MB over Vp, written AFTER vtrans
    float* ffn0 = (float*)(w + 0);                  // 32 MB over mem_bf+Kp (dead after fused)
    float* ffn1 = (float*)(w + (32LL << 20));       // 32 MB over Qp+mbits (dead after fused)

    // 1) casts (merged)
    cast_both<<<8192, 256, 0, stream>>>(memory, decoder, mem_bf, concat);
    // 2) weight transposes
    wtrans3<<<dim3(32, 32, 3), dim3(32, 8), 0, stream>>>(Wk, Wv, Wq, WkT, WvT, WqT);
    wtrans<<<dim3(32, 64), dim3(32, 8), 0, stream>>>(Wf, WfT, 2048, 1024);
    // 3) all three projections in one launch (z-batched, better occupancy)
    gemm_proj3<<<dim3(8, 64, 3), 256, 0, stream>>>(mem_bf, concat, WkT, WvT, WqT, Kp, Vp, Qp);
    // 4) V transpose per (b,h)
    vtrans<<<dim3(32, 4, 64), dim3(32, 8), 0, stream>>>(Vp, VT);
    // 5) mask bitpack (after vtrans: mbits overlays Vp)
    pack_mask<<<2048, 256, 0, stream>>>(mask, mbits);
    // 6) fused QK^T+softmax+qmask -> attns, and PV -> concat right half
    fused_attn<<<dim3(64, 8, 8), 256, 0, stream>>>(Qp, Kp, VT, mbits, qmask, attns, concat);
    // 7) FFN split-K: two partial fp32 buffers (1024 blocks resident)
    gemm_ffn<<<dim3(8, 64, 2), 256, 0, stream>>>(concat, WfT, ffn0, ffn1);
    // 8) bias + residual + LayerNorm -> x output
    ln_out<<<8192, 256, 0, stream>>>(ffn0, ffn1, decoder, bfv, gamma, beta, xout);
}